// Round 5
// baseline (253.820 us; speedup 1.0000x reference)
//
#include <hip/hip_runtime.h>
#include <hip/hip_cooperative_groups.h>

namespace cg = cooperative_groups;

// Problem constants (from reference)
#define BS    16
#define NA    3
#define NC    80
#define HH    76
#define WW    76
#define PLANE (HH*WW)            // 5776 (divisible by 4)
#define NCELL (BS*NA*HH*WW)      // 277248
#define NCH   (5+NC)             // 85

#define NV    (NCELL/4)          // 69312 vec4 groups
#define NTHR  256
#define NBLK  ((NV + NTHR - 1) / NTHR)   // 271 blocks (1084 waves, co-resident)
#define NACC  9
// acc indices: 0=cnt 1=ncnt 2=lx 3=ly 4=lw 5=lh 6=conf_m 7=conf_nm 8=cls
// d_ws: partials[NACC][NBLK] floats — every slot written every call, no init needed.

// exact BCE on logits: bce(sigmoid(z), t) = softplus(z) - t*z  (t in [0,1])
__device__ __forceinline__ float softplusf(float z) {
    return fmaxf(z, 0.0f) + __logf(1.0f + __expf(-fabsf(z)));
}

__global__ __launch_bounds__(NTHR) void yolo_fused(
    const float* __restrict__ inp,
    const int*   __restrict__ noobj,   // bool -> int32 per harness convention
    const float* __restrict__ tx,
    const float* __restrict__ ty,
    const float* __restrict__ tw,
    const float* __restrict__ th,
    const float* __restrict__ tconf,
    const float* __restrict__ tcls,
    const float* __restrict__ bls,
    float* __restrict__ partials,      // [NACC][NBLK] in d_ws
    float* __restrict__ out)
{
    float acc[NACC];
    #pragma unroll
    for (int k = 0; k < NACC; ++k) acc[k] = 0.0f;

    const int lane = threadIdx.x & 63;
    const int wave = threadIdx.x >> 6;
    const int v = blockIdx.x * NTHR + threadIdx.x;

    // Only the last 64 threads of the grid are out of range (69376-69312=64),
    // i.e. exactly one full wave — ballot/cooperative paths always see a fully
    // active wave.
    if (v < NV) {
        const int cell0 = v * 4;
        const int p     = cell0 % PLANE;   // 4 cells share one (b,a) plane
        const int ba    = cell0 / PLANE;

        // three independent 16B loads — all issued before any use
        const float4 zc4 = *(const float4*)(inp + ((size_t)ba * NCH + 4) * PLANE + p);
        const float4 m4  = *(const float4*)(tconf + cell0);
        const int4   n4  = *(const int4*)(noobj + cell0);

        const float zs[4] = {zc4.x, zc4.y, zc4.z, zc4.w};
        const float ms[4] = {m4.x, m4.y, m4.z, m4.w};
        const float ns[4] = {(float)n4.x, (float)n4.y, (float)n4.z, (float)n4.w};

        #pragma unroll
        for (int j = 0; j < 4; ++j) {
            const float z  = zs[j];
            const float m  = ms[j];
            const float nm = ns[j];
            const float bc = softplusf(z) - m * z;   // bce(sigmoid(z), m); tconf==mask
            acc[0] += m;
            acc[1] += nm;
            acc[6] += bc * m;
            acc[7] += bc * nm;
        }

        // ---- masked cells: whole wave cooperates on each one (rare: ~320 total)
        #pragma unroll
        for (int j = 0; j < 4; ++j) {
            unsigned long long bmask = __ballot(ms[j] > 0.0f);
            while (bmask) {
                const int src = __ffsll((long long)bmask) - 1;
                bmask &= bmask - 1;
                const int cell = __shfl(cell0, src, 64) + j;
                const int cba  = cell / PLANE;
                const int cp   = cell % PLANE;
                const float* cb = inp + (size_t)cba * NCH * PLANE + cp;
                const float* tc = tcls + (size_t)cell * NC;

                // classes: lane L -> class L; lanes 0..15 also class 64+L.
                const float z1 = cb[(5 + lane) * PLANE];
                const float t1 = tc[lane];
                float cls = softplusf(z1) - t1 * z1;
                if (lane < 16) {
                    const int c2 = 64 + lane;
                    const float z2 = cb[(5 + c2) * PLANE];
                    const float t2 = tc[c2];
                    cls += softplusf(z2) - t2 * z2;
                }
                acc[8] += cls;

                // coordinates: lanes 0..3 take x,y,w,h respectively (parallel loads)
                if (lane < 4) {
                    const float blsv = bls[cell];
                    const float z = cb[(size_t)lane * PLANE];
                    float term;
                    if (lane == 0)      term = (softplusf(z) - tx[cell] * z) * blsv;
                    else if (lane == 1) term = (softplusf(z) - ty[cell] * z) * blsv;
                    else if (lane == 2) { const float d = z - tw[cell]; term = d * d * blsv; }
                    else                { const float d = z - th[cell]; term = d * d * blsv; }
                    acc[2 + lane] += term;   // block reduction folds these correctly
                }
            }
        }
    }

    // ---- phase 1 block reduction: wave shuffle + LDS across 4 waves
    __shared__ float smem[NTHR / 64][NACC];
    #pragma unroll
    for (int k = 0; k < NACC; ++k) {
        float x = acc[k];
        #pragma unroll
        for (int off = 32; off > 0; off >>= 1) x += __shfl_down(x, off, 64);
        if (lane == 0) smem[wave][k] = x;
    }
    __syncthreads();
    if (threadIdx.x < NACC) {
        const int k = threadIdx.x;
        float x = 0.0f;
        #pragma unroll
        for (int w = 0; w < NTHR / 64; ++w) x += smem[w][k];
        partials[k * NBLK + blockIdx.x] = x;
    }

    // ---- grid-wide barrier, then block 0 finalizes
    __threadfence();
    cg::this_grid().sync();

    if (blockIdx.x == 0) {
        const int t = threadIdx.x;
        float a2[NACC];
        #pragma unroll
        for (int k = 0; k < NACC; ++k) {
            float x = partials[k * NBLK + t];                     // t < 256 <= NBLK
            if (t + 256 < NBLK) x += partials[k * NBLK + t + 256]; // t < 15
            a2[k] = x;
        }
        __syncthreads();   // smem reuse barrier
        #pragma unroll
        for (int k = 0; k < NACC; ++k) {
            float x = a2[k];
            #pragma unroll
            for (int off = 32; off > 0; off >>= 1) x += __shfl_down(x, off, 64);
            if (lane == 0) smem[wave][k] = x;
        }
        __syncthreads();
        if (threadIdx.x == 0) {
            float s[NACC];
            #pragma unroll
            for (int k = 0; k < NACC; ++k) {
                float x = 0.0f;
                #pragma unroll
                for (int w = 0; w < NTHR / 64; ++w) x += smem[w][k];
                s[k] = x;
            }
            const float cnt  = s[0];
            const float ncnt = s[1];
            out[0] = 2.5f * (s[2] + s[3] + s[4] + s[5]) / cnt
                   + s[6] / cnt + s[7] / ncnt
                   + s[8] / (cnt * (float)NC);
        }
    }
}

extern "C" void kernel_launch(void* const* d_in, const int* in_sizes, int n_in,
                              void* d_out, int out_size, void* d_ws, size_t ws_size,
                              hipStream_t stream) {
    const float* inp   = (const float*)d_in[0];
    // d_in[1] = mask (bool) — unused; m is recovered exactly from tconf
    const int*   noobj = (const int*)d_in[2];
    const float* tx    = (const float*)d_in[3];
    const float* ty    = (const float*)d_in[4];
    const float* tw    = (const float*)d_in[5];
    const float* th    = (const float*)d_in[6];
    const float* tconf = (const float*)d_in[7];
    const float* tcls  = (const float*)d_in[8];
    const float* bls   = (const float*)d_in[9];

    float* partials = (float*)d_ws;   // NACC*NBLK floats ~ 9.8 KB, fully overwritten
    float* out      = (float*)d_out;

    void* args[] = { (void*)&inp, (void*)&noobj, (void*)&tx, (void*)&ty,
                     (void*)&tw, (void*)&th, (void*)&tconf, (void*)&tcls,
                     (void*)&bls, (void*)&partials, (void*)&out };
    hipLaunchCooperativeKernel((const void*)yolo_fused,
                               dim3(NBLK), dim3(NTHR), args, 0, stream);
}

// Round 6
// 195.468 us; speedup vs baseline: 1.2985x; 1.2985x over previous
//
#include <hip/hip_runtime.h>

// Problem constants (from reference)
#define BS    16
#define NA    3
#define NC    80
#define HH    76
#define WW    76
#define PLANE (HH*WW)            // 5776 (divisible by 4)
#define NCELL (BS*NA*HH*WW)      // 277248
#define NCH   (5+NC)             // 85

#define NV    (NCELL/4)          // 69312 vec4 groups
#define NTHR  256
#define NBLK  ((NV + NTHR - 1) / NTHR)   // 271 blocks
#define NACC  9
// acc indices: 0=cnt 1=ncnt 2=lx 3=ly 4=lw 5=lh 6=conf_m 7=conf_nm 8=cls

// d_ws layout (32-bit words):
//  [0 .. NACC*NBLK)       float partials[NACC][NBLK]   (device-scope atomic stores)
//  [2560 .. 2560+NBLK)    uint  flags[NBLK]            (magic = 0x13579BDF + b)
// Nothing needs zero-init: flags are recognized by a per-block magic value that
// can never equal the 0xAAAAAAAA poison, and every slot is written every call.
#define WS_FLAGS 2560
#define MAGIC(b) (0x13579BDFu + (unsigned)(b))

// exact BCE on logits: bce(sigmoid(z), t) = softplus(z) - t*z  (t in [0,1])
__device__ __forceinline__ float softplusf(float z) {
    return fmaxf(z, 0.0f) + __logf(1.0f + __expf(-fabsf(z)));
}

__global__ __launch_bounds__(NTHR) void yolo_onenode(
    const float* __restrict__ inp,
    const int*   __restrict__ noobj,   // bool -> int32 per harness convention
    const float* __restrict__ tx,
    const float* __restrict__ ty,
    const float* __restrict__ tw,
    const float* __restrict__ th,
    const float* __restrict__ tconf,
    const float* __restrict__ tcls,
    const float* __restrict__ bls,
    float*       __restrict__ partials,  // d_ws base
    unsigned*    __restrict__ flags,     // d_ws + WS_FLAGS
    float*       __restrict__ out)
{
    float acc[NACC];
    #pragma unroll
    for (int k = 0; k < NACC; ++k) acc[k] = 0.0f;

    const int lane = threadIdx.x & 63;
    const int wave = threadIdx.x >> 6;
    const int v = blockIdx.x * NTHR + threadIdx.x;

    // Only the last 64 threads of the grid are out of range (69376-69312=64),
    // exactly one full wave — ballot/cooperative paths always see a full wave.
    if (v < NV) {
        const int cell0 = v * 4;
        const int p     = cell0 % PLANE;   // 4 cells share one (b,a) plane
        const int ba    = cell0 / PLANE;

        // three independent 16B loads — all issued before any use
        const float4 zc4 = *(const float4*)(inp + ((size_t)ba * NCH + 4) * PLANE + p);
        const float4 m4  = *(const float4*)(tconf + cell0);
        const int4   n4  = *(const int4*)(noobj + cell0);

        const float zs[4] = {zc4.x, zc4.y, zc4.z, zc4.w};
        const float ms[4] = {m4.x, m4.y, m4.z, m4.w};
        const float ns[4] = {(float)n4.x, (float)n4.y, (float)n4.z, (float)n4.w};

        #pragma unroll
        for (int j = 0; j < 4; ++j) {
            const float z  = zs[j];
            const float m  = ms[j];
            const float nm = ns[j];
            const float bc = softplusf(z) - m * z;   // bce(sigmoid(z), m); tconf==mask
            acc[0] += m;
            acc[1] += nm;
            acc[6] += bc * m;
            acc[7] += bc * nm;
        }

        // ---- masked cells: whole wave cooperates on each one (rare: ~320 total)
        #pragma unroll
        for (int j = 0; j < 4; ++j) {
            unsigned long long bmask = __ballot(ms[j] > 0.0f);
            while (bmask) {
                const int src = __ffsll((long long)bmask) - 1;
                bmask &= bmask - 1;
                const int cell = __shfl(cell0, src, 64) + j;
                const int cba  = cell / PLANE;
                const int cp   = cell % PLANE;
                const float* cb = inp + (size_t)cba * NCH * PLANE + cp;
                const float* tc = tcls + (size_t)cell * NC;

                // classes: lane L -> class L; lanes 0..15 also class 64+L.
                const float z1 = cb[(5 + lane) * PLANE];
                const float t1 = tc[lane];
                float cls = softplusf(z1) - t1 * z1;
                if (lane < 16) {
                    const int c2 = 64 + lane;
                    const float z2 = cb[(5 + c2) * PLANE];
                    const float t2 = tc[c2];
                    cls += softplusf(z2) - t2 * z2;
                }
                acc[8] += cls;

                // coordinates: lanes 0..3 take x,y,w,h (independent parallel loads)
                if (lane < 4) {
                    const float blsv = bls[cell];
                    const float z = cb[(size_t)lane * PLANE];
                    float term;
                    if (lane == 0)      term = (softplusf(z) - tx[cell] * z) * blsv;
                    else if (lane == 1) term = (softplusf(z) - ty[cell] * z) * blsv;
                    else if (lane == 2) { const float d = z - tw[cell]; term = d * d * blsv; }
                    else                { const float d = z - th[cell]; term = d * d * blsv; }
                    acc[2 + lane] += term;   // block reduction folds these correctly
                }
            }
        }
    }

    // ---- block reduction: wave shuffle + LDS across 4 waves
    __shared__ float smem[NTHR / 64][NACC];
    #pragma unroll
    for (int k = 0; k < NACC; ++k) {
        float x = acc[k];
        #pragma unroll
        for (int off = 32; off > 0; off >>= 1) x += __shfl_down(x, off, 64);
        if (lane == 0) smem[wave][k] = x;
    }
    __syncthreads();
    if (threadIdx.x < NACC) {
        const int k = threadIdx.x;
        float x = 0.0f;
        #pragma unroll
        for (int w = 0; w < NTHR / 64; ++w) x += smem[w][k];
        // device-scope store so the value is at the coherent point when the
        // flag (published after syncthreads) becomes visible
        atomicExch(&partials[k * NBLK + blockIdx.x], x);
    }
    __syncthreads();           // partial atomics complete before flag publish
    if (threadIdx.x == 0) {
        __threadfence();
        atomicExch(&flags[blockIdx.x], MAGIC(blockIdx.x));
    }

    // ---- only block 0 waits; everyone else retires immediately
    if (blockIdx.x != 0) return;

    const int t = threadIdx.x;
    float a2[NACC];

    // thread t consumes block t's partials (and block t+256's, for t < 15);
    // spin only on the flags this thread personally needs.
    {
        unsigned got;
        do {
            got = atomicAdd(&flags[t], 0u);
            if (got != MAGIC(t)) __builtin_amdgcn_s_sleep(1);
        } while (got != MAGIC(t));
        #pragma unroll
        for (int k = 0; k < NACC; ++k)
            a2[k] = atomicAdd(&partials[k * NBLK + t], 0.0f);
    }
    if (t + 256 < NBLK) {
        unsigned got;
        do {
            got = atomicAdd(&flags[t + 256], 0u);
            if (got != MAGIC(t + 256)) __builtin_amdgcn_s_sleep(1);
        } while (got != MAGIC(t + 256));
        #pragma unroll
        for (int k = 0; k < NACC; ++k)
            a2[k] += atomicAdd(&partials[k * NBLK + t + 256], 0.0f);
    }

    __syncthreads();   // smem reuse barrier
    #pragma unroll
    for (int k = 0; k < NACC; ++k) {
        float x = a2[k];
        #pragma unroll
        for (int off = 32; off > 0; off >>= 1) x += __shfl_down(x, off, 64);
        if (lane == 0) smem[wave][k] = x;
    }
    __syncthreads();
    if (threadIdx.x == 0) {
        float s[NACC];
        #pragma unroll
        for (int k = 0; k < NACC; ++k) {
            float x = 0.0f;
            #pragma unroll
            for (int w = 0; w < NTHR / 64; ++w) x += smem[w][k];
            s[k] = x;
        }
        const float cnt  = s[0];
        const float ncnt = s[1];
        out[0] = 2.5f * (s[2] + s[3] + s[4] + s[5]) / cnt
               + s[6] / cnt + s[7] / ncnt
               + s[8] / (cnt * (float)NC);
    }
}

extern "C" void kernel_launch(void* const* d_in, const int* in_sizes, int n_in,
                              void* d_out, int out_size, void* d_ws, size_t ws_size,
                              hipStream_t stream) {
    const float* inp   = (const float*)d_in[0];
    // d_in[1] = mask (bool) — unused; m is recovered exactly from tconf
    const int*   noobj = (const int*)d_in[2];
    const float* tx    = (const float*)d_in[3];
    const float* ty    = (const float*)d_in[4];
    const float* tw    = (const float*)d_in[5];
    const float* th    = (const float*)d_in[6];
    const float* tconf = (const float*)d_in[7];
    const float* tcls  = (const float*)d_in[8];
    const float* bls   = (const float*)d_in[9];

    float*    partials = (float*)d_ws;
    unsigned* flags    = (unsigned*)d_ws + WS_FLAGS;
    float*    out      = (float*)d_out;

    yolo_onenode<<<NBLK, NTHR, 0, stream>>>(inp, noobj, tx, ty, tw, th,
                                            tconf, tcls, bls,
                                            partials, flags, out);
}

// Round 7
// 190.209 us; speedup vs baseline: 1.3344x; 1.0277x over previous
//
#include <hip/hip_runtime.h>

// Problem constants (from reference)
#define BS    16
#define NA    3
#define NC    80
#define HH    76
#define WW    76
#define PLANE (HH*WW)            // 5776 (divisible by 4)
#define NCELL (BS*NA*HH*WW)      // 277248
#define NCH   (5+NC)             // 85

#define NV    (NCELL/4)          // 69312 vec4 groups
#define NTHR  256
#define NBLK  ((NV + NTHR - 1) / NTHR)   // 271 blocks
#define NACC  9
// acc indices: 0=cnt 1=ncnt 2=lx 3=ly 4=lw 5=lh 6=conf_m 7=conf_nm 8=cls
// d_ws: partials[NACC][NBLK] floats — every slot written every call, no init needed.

// exact BCE on logits: bce(sigmoid(z), t) = softplus(z) - t*z  (t in [0,1])
__device__ __forceinline__ float softplusf(float z) {
    return fmaxf(z, 0.0f) + __logf(1.0f + __expf(-fabsf(z)));
}

__global__ __launch_bounds__(NTHR) void yolo_main(
    const float* __restrict__ inp,
    const int*   __restrict__ noobj,   // bool -> int32 per harness convention
    const float* __restrict__ tx,
    const float* __restrict__ ty,
    const float* __restrict__ tw,
    const float* __restrict__ th,
    const float* __restrict__ tconf,
    const float* __restrict__ tcls,
    const float* __restrict__ bls,
    float* __restrict__ partials)      // [NACC][NBLK]
{
    float acc[NACC];
    #pragma unroll
    for (int k = 0; k < NACC; ++k) acc[k] = 0.0f;

    const int lane = threadIdx.x & 63;
    const int v = blockIdx.x * NTHR + threadIdx.x;

    // Only the very last 64 threads of the grid are out of bounds (69376-69312=64),
    // i.e. exactly one full wave — so ballot/cooperative paths below always run
    // with a fully-active wave.
    if (v < NV) {
        const int cell0 = v * 4;
        const int p     = cell0 % PLANE;   // 4 cells share one (b,a) plane
        const int ba    = cell0 / PLANE;

        // three independent 16B loads — all issued before any use
        const float4 zc4 = *(const float4*)(inp + ((size_t)ba * NCH + 4) * PLANE + p);
        const float4 m4  = *(const float4*)(tconf + cell0);
        const int4   n4  = *(const int4*)(noobj + cell0);

        const float zs[4] = {zc4.x, zc4.y, zc4.z, zc4.w};
        const float ms[4] = {m4.x, m4.y, m4.z, m4.w};
        const float ns[4] = {(float)n4.x, (float)n4.y, (float)n4.z, (float)n4.w};

        #pragma unroll
        for (int j = 0; j < 4; ++j) {
            const float z  = zs[j];
            const float m  = ms[j];
            const float nm = ns[j];
            const float bc = softplusf(z) - m * z;   // bce(sigmoid(z), m); tconf==mask
            acc[0] += m;
            acc[1] += nm;
            acc[6] += bc * m;
            acc[7] += bc * nm;
        }

        // ---- masked cells: whole wave cooperates on each one (rare: ~320 total)
        #pragma unroll
        for (int j = 0; j < 4; ++j) {
            unsigned long long bmask = __ballot(ms[j] > 0.0f);
            while (bmask) {
                const int src = __ffsll((long long)bmask) - 1;
                bmask &= bmask - 1;
                const int cell = __shfl(cell0, src, 64) + j;
                const int cba  = cell / PLANE;
                const int cp   = cell % PLANE;
                const float* cb = inp + (size_t)cba * NCH * PLANE + cp;
                const float* tc = tcls + (size_t)cell * NC;

                // classes: lane L -> class L; lanes 0..15 also class 64+L.
                const float z1 = cb[(5 + lane) * PLANE];
                const float t1 = tc[lane];
                float cls = softplusf(z1) - t1 * z1;
                if (lane < 16) {
                    const int c2 = 64 + lane;
                    const float z2 = cb[(5 + c2) * PLANE];
                    const float t2 = tc[c2];
                    cls += softplusf(z2) - t2 * z2;
                }
                acc[8] += cls;

                // coordinates: lanes 0..3 take x,y,w,h respectively (parallel loads)
                if (lane < 4) {
                    const float blsv = bls[cell];
                    const float z = cb[(size_t)lane * PLANE];
                    float term;
                    if (lane == 0)      term = (softplusf(z) - tx[cell] * z) * blsv;
                    else if (lane == 1) term = (softplusf(z) - ty[cell] * z) * blsv;
                    else if (lane == 2) { const float d = z - tw[cell]; term = d * d * blsv; }
                    else                { const float d = z - th[cell]; term = d * d * blsv; }
                    acc[2 + lane] += term;   // block reduction folds these correctly
                }
            }
        }
    }

    // block reduction: wave64 shuffle, then LDS across 4 waves
    __shared__ float smem[NTHR / 64][NACC];
    const int wave = threadIdx.x >> 6;
    #pragma unroll
    for (int k = 0; k < NACC; ++k) {
        float x = acc[k];
        #pragma unroll
        for (int off = 32; off > 0; off >>= 1) x += __shfl_down(x, off, 64);
        if (lane == 0) smem[wave][k] = x;
    }
    __syncthreads();
    if (threadIdx.x < NACC) {
        const int k = threadIdx.x;
        float x = 0.0f;
        #pragma unroll
        for (int w = 0; w < NTHR / 64; ++w) x += smem[w][k];
        partials[k * NBLK + blockIdx.x] = x;
    }
}

#define FTHR 320   // 5 waves >= NBLK=271
__global__ __launch_bounds__(FTHR) void yolo_final(
    const float* __restrict__ partials,
    float* __restrict__ out)
{
    float acc[NACC];
    #pragma unroll
    for (int k = 0; k < NACC; ++k)
        acc[k] = (threadIdx.x < NBLK) ? partials[k * NBLK + threadIdx.x] : 0.0f;

    __shared__ float smem[FTHR / 64][NACC];
    const int lane = threadIdx.x & 63;
    const int wave = threadIdx.x >> 6;
    #pragma unroll
    for (int k = 0; k < NACC; ++k) {
        float x = acc[k];
        #pragma unroll
        for (int off = 32; off > 0; off >>= 1) x += __shfl_down(x, off, 64);
        if (lane == 0) smem[wave][k] = x;
    }
    __syncthreads();
    if (threadIdx.x == 0) {
        float s[NACC];
        #pragma unroll
        for (int k = 0; k < NACC; ++k) {
            float x = 0.0f;
            #pragma unroll
            for (int w = 0; w < FTHR / 64; ++w) x += smem[w][k];
            s[k] = x;
        }
        const float cnt  = s[0];
        const float ncnt = s[1];
        out[0] = 2.5f * (s[2] + s[3] + s[4] + s[5]) / cnt
               + s[6] / cnt + s[7] / ncnt
               + s[8] / (cnt * (float)NC);
    }
}

extern "C" void kernel_launch(void* const* d_in, const int* in_sizes, int n_in,
                              void* d_out, int out_size, void* d_ws, size_t ws_size,
                              hipStream_t stream) {
    const float* inp   = (const float*)d_in[0];
    // d_in[1] = mask (bool) — unused; m is recovered exactly from tconf
    const int*   noobj = (const int*)d_in[2];
    const float* tx    = (const float*)d_in[3];
    const float* ty    = (const float*)d_in[4];
    const float* tw    = (const float*)d_in[5];
    const float* th    = (const float*)d_in[6];
    const float* tconf = (const float*)d_in[7];
    const float* tcls  = (const float*)d_in[8];
    const float* bls   = (const float*)d_in[9];

    float* partials = (float*)d_ws;            // NACC*NBLK floats ~ 9.8 KB, fully overwritten
    float* out      = (float*)d_out;

    yolo_main<<<NBLK, NTHR, 0, stream>>>(inp, noobj, tx, ty, tw, th,
                                         tconf, tcls, bls, partials);
    yolo_final<<<1, FTHR, 0, stream>>>(partials, out);
}